// Round 1
// baseline (233.564 us; speedup 1.0000x reference)
//
#include <hip/hip_runtime.h>
#include <hip/hip_bf16.h>
#include <stdint.h>

#define B_ 4
#define N_ 1024
#define C_ 768
#define H_ 12
#define D_ 64

typedef unsigned short u16;
typedef __attribute__((ext_vector_type(8))) short bf16x8;
typedef __attribute__((ext_vector_type(4))) float f32x4;

#define AS1 __attribute__((address_space(1)))
#define AS3 __attribute__((address_space(3)))

__device__ __forceinline__ u16 f2b(float f) {
    union { float f; uint32_t u; } x; x.f = f;
    uint32_t r = x.u + 0x7fffu + ((x.u >> 16) & 1u);
    return (u16)(r >> 16);
}
__device__ __forceinline__ float b2f(u16 b) {
    union { uint32_t u; float f; } x; x.u = ((uint32_t)b) << 16;
    return x.f;
}

__device__ __forceinline__ void gload16(const void* g, void* lds) {
    __builtin_amdgcn_global_load_lds((const AS1 uint32_t*)g, (AS3 uint32_t*)lds, 16, 0, 0);
}

// Stage a (rows x 64) bf16 tile from row-major src (leading dim ld, elements)
// into LDS. LDS layout: row stride 128B, 16B-slot XOR-swizzle byte^=(row&7)<<4.
// global_load_lds writes linearly (base + lane*16), so the swizzle is applied
// by permuting the per-lane GLOBAL source (inverse == same XOR, involution).
__device__ __forceinline__ void stage_tile(const u16* __restrict__ g, int ld,
                                           u16* lds, int rows, int w, int l) {
    int nchunk = rows >> 3;              // 1KB chunks (8 rows each)
    for (int j = w; j < nchunk; j += 4) {
        int base = j << 10;              // wave-uniform LDS byte base
        int lanebyte = base + (l << 4);
        int row  = lanebyte >> 7;
        int slot = ((lanebyte >> 4) & 7) ^ (row & 7);
        const u16* src = g + row * ld + (slot << 3);
        gload16(src, (char*)lds + base);
    }
}

__device__ __forceinline__ bf16x8 frag_ld(const u16* lds, int row, int k) {
    int byte = (row << 7) + (k << 1);
    byte ^= (row & 7) << 4;
    return *(const bf16x8*)((const char*)lds + byte);
}

__device__ __forceinline__ f32x4 mfma_bf16(bf16x8 a, bf16x8 b, f32x4 c) {
    return __builtin_amdgcn_mfma_f32_16x16x32_bf16(a, b, c, 0, 0, 0);
}

// ---------------- converts ----------------

__global__ void k_cvt(const float* __restrict__ in, u16* __restrict__ outb) {
    int i = blockIdx.x * blockDim.x + threadIdx.x;
    float4 v = ((const float4*)in)[i];
    ushort4 o;
    o.x = f2b(v.x); o.y = f2b(v.y); o.z = f2b(v.z); o.w = f2b(v.w);
    ((ushort4*)outb)[i] = o;
}

// f32 [R][Cc] -> bf16 transposed [Cc][R]
__global__ void k_transcvt(const float* __restrict__ in, u16* __restrict__ outb,
                           int R, int Cc) {
    __shared__ float t[32][33];
    int bc = blockIdx.x * 32, br = blockIdx.y * 32;
    int tid = threadIdx.x;
    for (int i = 0; i < 4; i++) {
        int idx = i * 256 + tid; int r = idx >> 5, c = idx & 31;
        t[r][c] = in[(size_t)(br + r) * Cc + bc + c];
    }
    __syncthreads();
    for (int i = 0; i < 4; i++) {
        int idx = i * 256 + tid; int c = idx >> 5, r = idx & 31;
        outb[(size_t)(bc + c) * R + br + r] = f2b(t[r][c]);
    }
}

// vT[b][h][dd][n] = qkv[b][n][2][h][dd]
__global__ void k_vT(const u16* __restrict__ qkv, u16* __restrict__ vT) {
    __shared__ u16 t[64][72];
    int blk = blockIdx.x;
    int nt = blk & 15, h = (blk >> 4) % H_, b = blk / (H_ * 16);
    int tid = threadIdx.x;
    const u16* src = qkv + ((size_t)(b * N_ + nt * 64)) * (3 * C_) + 2 * C_ + h * 64;
    for (int i = 0; i < 16; i++) {
        int idx = i * 256 + tid; int n = idx >> 6, dd = idx & 63;
        t[n][dd] = src[(size_t)n * (3 * C_) + dd];
    }
    __syncthreads();
    u16* dst = vT + ((size_t)(b * H_ + h) * D_) * N_ + nt * 64;
    for (int i = 0; i < 16; i++) {
        int idx = i * 256 + tid; int dd = idx >> 6, n = idx & 63;
        dst[(size_t)dd * N_ + n] = t[n][dd];
    }
}

// ---------------- GEMM: qkv = x @ W_qkv (bf16, q-part pre-scaled) ----------------

__global__ __launch_bounds__(256, 2)
void k_gemm_qkv(const u16* __restrict__ xb, const u16* __restrict__ WT,
                u16* __restrict__ qkv) {
    __shared__ __attribute__((aligned(128))) u16 As[128 * 64];
    __shared__ __attribute__((aligned(128))) u16 Bs[128 * 64];
    int tid = threadIdx.x, w = tid >> 6, l = tid & 63;
    int row0 = blockIdx.x * 128, col0 = blockIdx.y * 128;
    f32x4 acc[4][4] = {};
    int wr = (w >> 1) * 64, wc = (w & 1) * 64;
    int fr = l & 15, fq = l >> 4;
    for (int k0 = 0; k0 < C_; k0 += 64) {
        stage_tile(xb + (size_t)row0 * C_ + k0, C_, As, 128, w, l);
        stage_tile(WT + (size_t)col0 * C_ + k0, C_, Bs, 128, w, l);
        __syncthreads();
        #pragma unroll
        for (int kk = 0; kk < 64; kk += 32) {
            bf16x8 af[4], bfr[4];
            #pragma unroll
            for (int i = 0; i < 4; i++) af[i] = frag_ld(As, wr + i * 16 + fr, kk + fq * 8);
            #pragma unroll
            for (int j = 0; j < 4; j++) bfr[j] = frag_ld(Bs, wc + j * 16 + fr, kk + fq * 8);
            #pragma unroll
            for (int i = 0; i < 4; i++)
                #pragma unroll
                for (int j = 0; j < 4; j++)
                    acc[i][j] = mfma_bf16(af[i], bfr[j], acc[i][j]);
        }
        __syncthreads();
    }
    #pragma unroll
    for (int i = 0; i < 4; i++) {
        #pragma unroll
        for (int j = 0; j < 4; j++) {
            int col = col0 + wc + j * 16 + fr;
            float s = (col < C_) ? 0.125f : 1.0f;   // q scale = d^-0.5 = 1/8
            #pragma unroll
            for (int r = 0; r < 4; r++) {
                int row = row0 + wr + i * 16 + fq * 4 + r;
                qkv[(size_t)row * (3 * C_) + col] = f2b(acc[i][j][r] * s);
            }
        }
    }
}

// ---------------- GEMM: S[b][n][h][m] = q . k ----------------

__global__ __launch_bounds__(256, 2)
void k_gemm_qk(const u16* __restrict__ qkv, u16* __restrict__ S) {
    __shared__ __attribute__((aligned(128))) u16 As[128 * 64];
    __shared__ __attribute__((aligned(128))) u16 Bs[128 * 64];
    int tid = threadIdx.x, w = tid >> 6, l = tid & 63;
    int blk = blockIdx.x;
    int bh = blk >> 6, t = blk & 63;
    int b = bh / H_, h = bh % H_;
    int tm = t >> 3, tn = t & 7;
    const u16* qbase = qkv + (size_t)(b * N_) * (3 * C_) + h * 64;
    const u16* kbase = qkv + (size_t)(b * N_) * (3 * C_) + C_ + h * 64;
    f32x4 acc[4][4] = {};
    int wr = (w >> 1) * 64, wc = (w & 1) * 64;
    int fr = l & 15, fq = l >> 4;
    stage_tile(qbase + (size_t)(tm * 128) * (3 * C_), 3 * C_, As, 128, w, l);
    stage_tile(kbase + (size_t)(tn * 128) * (3 * C_), 3 * C_, Bs, 128, w, l);
    __syncthreads();
    #pragma unroll
    for (int kk = 0; kk < 64; kk += 32) {
        bf16x8 af[4], bfr[4];
        #pragma unroll
        for (int i = 0; i < 4; i++) af[i] = frag_ld(As, wr + i * 16 + fr, kk + fq * 8);
        #pragma unroll
        for (int j = 0; j < 4; j++) bfr[j] = frag_ld(Bs, wc + j * 16 + fr, kk + fq * 8);
        #pragma unroll
        for (int i = 0; i < 4; i++)
            #pragma unroll
            for (int j = 0; j < 4; j++)
                acc[i][j] = mfma_bf16(af[i], bfr[j], acc[i][j]);
    }
    #pragma unroll
    for (int i = 0; i < 4; i++) {
        #pragma unroll
        for (int j = 0; j < 4; j++) {
            int col = tn * 128 + wc + j * 16 + fr;
            #pragma unroll
            for (int r = 0; r < 4; r++) {
                int row = tm * 128 + wr + i * 16 + fq * 4 + r;
                S[((size_t)(b * N_ + row) * H_ + h) * N_ + col] = f2b(acc[i][j][r]);
            }
        }
    }
}

// ---------------- fused: W_l head-mix + softmax + W_w head-mix ----------------
// one block per (b,n); thread owns 4 consecutive m for all 12 heads.
// b_l is constant along m => softmax-invariant => dropped.

__global__ __launch_bounds__(256, 2)
void k_mix_softmax(const u16* __restrict__ S, u16* __restrict__ Pw,
                   const float* __restrict__ Wl, const float* __restrict__ Ww,
                   const float* __restrict__ bw) {
    __shared__ float sWl[144], sWw[144], sbw[12];
    __shared__ float red[4][12];
    int tid = threadIdx.x;
    if (tid < 144) { sWl[tid] = Wl[tid]; sWw[tid] = Ww[tid]; }
    if (tid < 12) sbw[tid] = bw[tid];
    int blk = blockIdx.x;
    int b = blk >> 10, n = blk & 1023;
    const u16* srow = S + ((size_t)(b * N_ + n) * H_) * N_;
    float sv[12][4];
    #pragma unroll
    for (int h = 0; h < 12; h++) {
        ushort4 x = *(const ushort4*)(srow + (size_t)h * N_ + tid * 4);
        sv[h][0] = b2f(x.x); sv[h][1] = b2f(x.y);
        sv[h][2] = b2f(x.z); sv[h][3] = b2f(x.w);
    }
    __syncthreads();
    float T[12][4];
    #pragma unroll
    for (int g = 0; g < 12; g++) {
        float t0 = 0.f, t1 = 0.f, t2 = 0.f, t3 = 0.f;
        #pragma unroll
        for (int h = 0; h < 12; h++) {
            float wv = sWl[h * 12 + g];
            t0 += wv * sv[h][0]; t1 += wv * sv[h][1];
            t2 += wv * sv[h][2]; t3 += wv * sv[h][3];
        }
        T[g][0] = t0; T[g][1] = t1; T[g][2] = t2; T[g][3] = t3;
    }
    // block-wide row max per g
    float gmax[12];
    #pragma unroll
    for (int g = 0; g < 12; g++) {
        float m = fmaxf(fmaxf(T[g][0], T[g][1]), fmaxf(T[g][2], T[g][3]));
        for (int off = 32; off; off >>= 1) m = fmaxf(m, __shfl_xor(m, off));
        if ((tid & 63) == 0) red[tid >> 6][g] = m;
    }
    __syncthreads();
    #pragma unroll
    for (int g = 0; g < 12; g++)
        gmax[g] = fmaxf(fmaxf(red[0][g], red[1][g]), fmaxf(red[2][g], red[3][g]));
    __syncthreads();
    // exp + block-wide sum per g
    float Z[12];
    #pragma unroll
    for (int g = 0; g < 12; g++) {
        float s = 0.f;
        #pragma unroll
        for (int mi = 0; mi < 4; mi++) {
            T[g][mi] = __expf(T[g][mi] - gmax[g]);
            s += T[g][mi];
        }
        for (int off = 32; off; off >>= 1) s += __shfl_xor(s, off);
        if ((tid & 63) == 0) red[tid >> 6][g] = s;
    }
    __syncthreads();
    #pragma unroll
    for (int g = 0; g < 12; g++)
        Z[g] = 1.0f / (red[0][g] + red[1][g] + red[2][g] + red[3][g]);
    #pragma unroll
    for (int h = 0; h < 12; h++) {
        T[h][0] *= Z[h]; T[h][1] *= Z[h]; T[h][2] *= Z[h]; T[h][3] *= Z[h];
    }
    // W_w mix + b_w, write Pw[b][g][n][m] bf16
    #pragma unroll
    for (int g = 0; g < 12; g++) {
        float o0 = sbw[g], o1 = sbw[g], o2 = sbw[g], o3 = sbw[g];
        #pragma unroll
        for (int h = 0; h < 12; h++) {
            float wv = sWw[h * 12 + g];
            o0 += wv * T[h][0]; o1 += wv * T[h][1];
            o2 += wv * T[h][2]; o3 += wv * T[h][3];
        }
        ushort4 o;
        o.x = f2b(o0); o.y = f2b(o1); o.z = f2b(o2); o.w = f2b(o3);
        *(ushort4*)(Pw + ((size_t)(b * H_ + g) * N_ + n) * N_ + tid * 4) = o;
    }
}

// ---------------- GEMM: u = Pw @ v  (MODE 0, writes u and uT)
//                  w = Pw @ u  (MODE 1, fused combine -> o) ----------------

template <int MODE>
__global__ __launch_bounds__(256, 2)
void k_gemm_av(const u16* __restrict__ Pw, const u16* __restrict__ BT,
               u16* __restrict__ out0, u16* __restrict__ out1,
               const u16* __restrict__ ubuf, const float* __restrict__ lamb) {
    __shared__ __attribute__((aligned(128))) u16 As[128 * 64];
    __shared__ __attribute__((aligned(128))) u16 Bs[64 * 64];
    int tid = threadIdx.x, w = tid >> 6, l = tid & 63;
    int blk = blockIdx.x;
    int bh = blk >> 3, tm = blk & 7;
    int b = bh / H_, h = bh % H_;
    const u16* Abase = Pw + ((size_t)bh * N_ + tm * 128) * N_;
    const u16* Bbase = BT + (size_t)bh * D_ * N_;
    f32x4 acc[2][4] = {};
    int wrow = w * 32;
    int fr = l & 15, fq = l >> 4;
    for (int k0 = 0; k0 < N_; k0 += 64) {
        stage_tile(Abase + k0, N_, As, 128, w, l);
        stage_tile(Bbase + k0, N_, Bs, 64, w, l);
        __syncthreads();
        #pragma unroll
        for (int kk = 0; kk < 64; kk += 32) {
            bf16x8 af[2], bfr[4];
            #pragma unroll
            for (int i = 0; i < 2; i++) af[i] = frag_ld(As, wrow + i * 16 + fr, kk + fq * 8);
            #pragma unroll
            for (int j = 0; j < 4; j++) bfr[j] = frag_ld(Bs, j * 16 + fr, kk + fq * 8);
            #pragma unroll
            for (int i = 0; i < 2; i++)
                #pragma unroll
                for (int j = 0; j < 4; j++)
                    acc[i][j] = mfma_bf16(af[i], bfr[j], acc[i][j]);
        }
        __syncthreads();
    }
    float lam = (MODE == 1) ? lamb[h] : 0.f;
    #pragma unroll
    for (int i = 0; i < 2; i++) {
        #pragma unroll
        for (int j = 0; j < 4; j++) {
            int col = j * 16 + fr;
            #pragma unroll
            for (int r = 0; r < 4; r++) {
                int row = tm * 128 + wrow + i * 16 + fq * 4 + r;
                if (MODE == 0) {
                    u16 val = f2b(acc[i][j][r]);
                    out0[((size_t)bh * N_ + row) * D_ + col] = val;       // u
                    out1[((size_t)bh * D_ + col) * N_ + row] = val;       // uT
                } else {
                    float uv = b2f(ubuf[((size_t)bh * N_ + row) * D_ + col]);
                    float res = (1.f - 2.f * lam) * uv + 3.f * lam * acc[i][j][r];
                    out0[(size_t)(b * N_ + row) * C_ + h * 64 + col] = f2b(res);
                }
            }
        }
    }
}

// ---------------- GEMM: out = o @ W_proj + b_proj (f32 out) ----------------

__global__ __launch_bounds__(256, 2)
void k_gemm_proj(const u16* __restrict__ o, const u16* __restrict__ WT,
                 const float* __restrict__ bias, float* __restrict__ out) {
    __shared__ __attribute__((aligned(128))) u16 As[128 * 64];
    __shared__ __attribute__((aligned(128))) u16 Bs[128 * 64];
    int tid = threadIdx.x, w = tid >> 6, l = tid & 63;
    int row0 = blockIdx.x * 128, col0 = blockIdx.y * 128;
    f32x4 acc[4][4] = {};
    int wr = (w >> 1) * 64, wc = (w & 1) * 64;
    int fr = l & 15, fq = l >> 4;
    for (int k0 = 0; k0 < C_; k0 += 64) {
        stage_tile(o + (size_t)row0 * C_ + k0, C_, As, 128, w, l);
        stage_tile(WT + (size_t)col0 * C_ + k0, C_, Bs, 128, w, l);
        __syncthreads();
        #pragma unroll
        for (int kk = 0; kk < 64; kk += 32) {
            bf16x8 af[4], bfr[4];
            #pragma unroll
            for (int i = 0; i < 4; i++) af[i] = frag_ld(As, wr + i * 16 + fr, kk + fq * 8);
            #pragma unroll
            for (int j = 0; j < 4; j++) bfr[j] = frag_ld(Bs, wc + j * 16 + fr, kk + fq * 8);
            #pragma unroll
            for (int i = 0; i < 4; i++)
                #pragma unroll
                for (int j = 0; j < 4; j++)
                    acc[i][j] = mfma_bf16(af[i], bfr[j], acc[i][j]);
        }
        __syncthreads();
    }
    #pragma unroll
    for (int i = 0; i < 4; i++) {
        #pragma unroll
        for (int j = 0; j < 4; j++) {
            int col = col0 + wc + j * 16 + fr;
            float bv = bias[col];
            #pragma unroll
            for (int r = 0; r < 4; r++) {
                int row = row0 + wr + i * 16 + fq * 4 + r;
                out[(size_t)row * C_ + col] = acc[i][j][r] + bv;
            }
        }
    }
}

// ---------------- launch ----------------

extern "C" void kernel_launch(void* const* d_in, const int* in_sizes, int n_in,
                              void* d_out, int out_size, void* d_ws, size_t ws_size,
                              hipStream_t stream) {
    const float* x     = (const float*)d_in[0];
    const float* Wqkv  = (const float*)d_in[1];
    const float* Wproj = (const float*)d_in[2];
    const float* bproj = (const float*)d_in[3];
    const float* Wl    = (const float*)d_in[4];
    // d_in[5] = b_l: softmax-invariant, unused
    const float* Ww    = (const float*)d_in[6];
    const float* bw    = (const float*)d_in[7];
    const float* lamb  = (const float*)d_in[8];
    float* out = (float*)d_out;
    char* ws = (char*)d_ws;

    constexpr size_t SZ_S   = (size_t)B_ * N_ * H_ * N_ * 2;   // 100,663,296
    constexpr size_t SZ_QKV = (size_t)B_ * N_ * 3 * C_ * 2;    //  18,874,368
    constexpr size_t SZ_U   = (size_t)B_ * H_ * N_ * D_ * 2;   //   6,291,456
    constexpr size_t SZ_XB  = (size_t)B_ * N_ * C_ * 2;        //   6,291,456
    constexpr size_t SZ_WQT = (size_t)C_ * 3 * C_ * 2;         //   3,538,944

    u16* S      = (u16*)(ws);
    u16* Pw     = (u16*)(ws + SZ_S);
    u16* qkv    = (u16*)(ws + 2 * SZ_S);
    u16* u      = qkv;                                  // reuse: qkv dead after S/vT
    u16* uT     = (u16*)(ws + 2 * SZ_S + SZ_U);
    u16* o      = (u16*)(ws + 2 * SZ_S + 2 * SZ_U);
    u16* xb     = (u16*)(ws + 2 * SZ_S + SZ_QKV);
    u16* vT     = xb;                                   // reuse: xb dead after qkv GEMM
    u16* WqkvT  = (u16*)(ws + 2 * SZ_S + SZ_QKV + SZ_XB);
    u16* WprojT = (u16*)(ws + 2 * SZ_S + SZ_QKV + SZ_XB + SZ_WQT);
    // total: ~231.2 MB

    k_cvt<<<3072, 256, 0, stream>>>(x, xb);
    k_transcvt<<<dim3(72, 24), 256, 0, stream>>>(Wqkv, WqkvT, C_, 3 * C_);
    k_transcvt<<<dim3(24, 24), 256, 0, stream>>>(Wproj, WprojT, C_, C_);
    k_gemm_qkv<<<dim3(32, 18), 256, 0, stream>>>(xb, WqkvT, qkv);
    k_vT<<<B_ * H_ * 16, 256, 0, stream>>>(qkv, vT);
    k_gemm_qk<<<B_ * H_ * 64, 256, 0, stream>>>(qkv, S);
    k_mix_softmax<<<B_ * N_, 256, 0, stream>>>(S, Pw, Wl, Ww, bw);
    k_gemm_av<0><<<B_ * H_ * 8, 256, 0, stream>>>(Pw, vT, u, uT, nullptr, nullptr);
    k_gemm_av<1><<<B_ * H_ * 8, 256, 0, stream>>>(Pw, uT, o, nullptr, u, lamb);
    k_gemm_proj<<<dim3(32, 6), 256, 0, stream>>>(o, WprojT, bproj, out);
}